// Round 6
// baseline (709.025 us; speedup 1.0000x reference)
//
#include <hip/hip_runtime.h>
#include <math.h>

#define VOXN 32768

// ---- workspace layout (float offsets) ----
constexpr int OFF_STATS_Y   = 0;        // 512
constexpr int OFF_STATS_X2P = 512;      // 256
constexpr int OFF_STATS_H   = 768;      // 512
constexpr int OFF_TPAR      = 1280;     // 1024*16 packed tap params
constexpr int OFF_W1T       = 17664;    // 65536: [g*2+oh][c(256)][o(32)]
constexpr int OFF_W2T       = 83200;    // 32768
constexpr int OFF_W3AT      = 115968;   // 4096
constexpr int OFF_W3BT      = 120064;   // 5120
constexpr int OFF_W3CT      = 125184;   // 6144
constexpr int OFF_W3DT      = 131328;   // 7168
constexpr int OFF_W4T       = 138496;   // 2048
constexpr int OFF_YH        = 140544;   // 8388608 (y, later H)
constexpr int OFF_X2P       = 8529152;  // 4194304 (x2pre; ALSO hosts pvol98 early)
constexpr int OFF_PVOL      = OFF_X2P;  // 941192 floats (98^3), dead before s2 writes x2p

#define FMA4(A, W, X) { (A).x = fmaf((W).x, (X), (A).x); (A).y = fmaf((W).y, (X), (A).y); \
                        (A).z = fmaf((W).z, (X), (A).z); (A).w = fmaf((W).w, (X), (A).w); }
#define RELU4(A) { (A).x = fmaxf((A).x, 0.f); (A).y = fmaxf((A).y, 0.f); \
                   (A).z = fmaxf((A).z, 0.f); (A).w = fmaxf((A).w, 0.f); }
#define ZERO4(A) float4 A; (A).x = 0.f; (A).y = 0.f; (A).z = 0.f; (A).w = 0.f;

#define BFLY(s, q) { s += __shfl_xor(s, 32, 64); q += __shfl_xor(q, 32, 64); \
                     s += __shfl_xor(s, 16, 64); q += __shfl_xor(q, 16, 64); \
                     s += __shfl_xor(s,  8, 64); q += __shfl_xor(q,  8, 64); \
                     s += __shfl_xor(s,  4, 64); q += __shfl_xor(q,  4, 64); \
                     s += __shfl_xor(s,  2, 64); q += __shfl_xor(q,  2, 64); \
                     s += __shfl_xor(s,  1, 64); q += __shfl_xor(q,  1, 64); }
#define STASH1(V, O) { float s_ = (V), q_ = (V) * (V); BFLY(s_, q_) \
                       if (lane == (O)) { ms = s_; mq = q_; } }
#define STASH4(A, O0) STASH1((A).x, (O0)+0) STASH1((A).y, (O0)+1) \
                      STASH1((A).z, (O0)+2) STASH1((A).w, (O0)+3)

// ---------------- S0: setup ----------------
__global__ void s0_setup(const float* __restrict__ images, const float* __restrict__ offset1,
                         const float* __restrict__ w1, const float* __restrict__ w2,
                         const float* __restrict__ w3a, const float* __restrict__ w3b,
                         const float* __restrict__ w3c, const float* __restrict__ w3d,
                         const float* __restrict__ w4, float* __restrict__ ws)
{
  const int idx = blockIdx.x * blockDim.x + threadIdx.x;
  const int stride = gridDim.x * blockDim.x;
  for (int i = idx; i < 1280; i += stride) ws[i] = 0.f;
  float* pvol = ws + OFF_PVOL;
  for (int i = idx; i < 941192; i += stride) {
    int x = i % 98, t = i / 98, y = t % 98, z = t / 98;
    float val = 0.f;
    if (x >= 33 && x < 65 && y >= 33 && y < 65 && z >= 33 && z < 65)
      val = images[((z - 33) * 32 + (y - 33)) * 32 + (x - 33)];
    pvol[i] = val;
  }
  for (int k = idx; k < 1024; k += stride) {
    float* tp = ws + OFF_TPAR + k * 16;
    for (int s = 0; s < 2; ++s) {
      float ox = fminf(fmaxf(offset1[k * 6 + s * 3 + 0] * 16.f, -1000.f), 1000.f);
      float oy = fminf(fmaxf(offset1[k * 6 + s * 3 + 1] * 16.f, -1000.f), 1000.f);
      float oz = fminf(fmaxf(offset1[k * 6 + s * 3 + 2] * 16.f, -1000.f), 1000.f);
      float fxf = floorf(ox), fyf = floorf(oy), fzf = floorf(oz);
      float fx = ox - fxf, fy = oy - fyf, fz = oz - fzf;
      int sx = (int)fxf, sy = (int)fyf, sz = (int)fzf;
      bool valid = (sx >= -33 && sx <= 32) && (sy >= -33 && sy <= 32) && (sz >= -33 && sz <= 32);
      if (!valid) { sx = sy = sz = 0; }
      float vm = valid ? 1.f : 0.f;
      int c0 = (sz + 33) * 9604 + (sy + 33) * 98 + (sx + 33);
      float sgn = s ? -1.f : 1.f;
      float wy0 = 1.f - fy, wy1 = fy, wz0 = 1.f - fz, wz1 = fz;
      tp[s * 8 + 0] = __int_as_float(c0);
      tp[s * 8 + 1] = vm * (1.f - fx);
      tp[s * 8 + 2] = vm * fx;
      tp[s * 8 + 3] = vm * sgn * wz0 * wy0;
      tp[s * 8 + 4] = vm * sgn * wz0 * wy1;
      tp[s * 8 + 5] = vm * sgn * wz1 * wy0;
      tp[s * 8 + 6] = vm * sgn * wz1 * wy1;
      tp[s * 8 + 7] = 0.f;
    }
  }
  // w1t: [g*2+oh][c][o32] for contiguous per-block staging
  for (int i = idx; i < 65536; i += stride) {
    int o32 = i & 31, c = (i >> 5) & 255, goh = i >> 13;
    int g = goh >> 1, oh = goh & 1;
    ws[OFF_W1T + i] = w1[g * 16384 + (oh * 32 + o32) * 256 + c];
  }
  for (int i = idx; i < 32768; i += stride) { int o = i & 127, c = i >> 7; ws[OFF_W2T + i] = w2[o * 256 + c]; }
  for (int i = idx; i < 4096;  i += stride) { int o = i & 31,  c = i >> 5; ws[OFF_W3AT + i] = w3a[o * 128 + c]; }
  for (int i = idx; i < 5120;  i += stride) { int o = i & 31,  c = i >> 5; ws[OFF_W3BT + i] = w3b[o * 160 + c]; }
  for (int i = idx; i < 6144;  i += stride) { int o = i & 31,  c = i >> 5; ws[OFF_W3CT + i] = w3c[o * 192 + c]; }
  for (int i = idx; i < 7168;  i += stride) { int o = i & 31,  c = i >> 5; ws[OFF_W3DT + i] = w3d[o * 224 + c]; }
  for (int i = idx; i < 2048;  i += stride) { int l = i & 7,   c = i >> 3; ws[OFF_W4T + i] = w4[l * 256 + c]; }
}

// ---------------- S1: fused gather + grouped GEMM ----------------
// grid (128 voxel-tiles, 4 groups, 2 o-halves); 256 thr; 32 outputs/block.
// 4 blocks/CU (33 KB LDS) -> 16 waves/CU for latency hiding.
__global__ __launch_bounds__(256) void s1_gather_gemm(
    const float* __restrict__ pvol, const float* __restrict__ tpar,
    const float* __restrict__ w1t, float* __restrict__ y, float* __restrict__ stats_y)
{
  __shared__ float wlds[128 * 32];    // 16 KB: half-K weight tile (32 outputs)
  __shared__ float tplds[256 * 16];   // 16 KB: tap params for this group
  __shared__ float redS[4][32], redQ[4][32];
  const int tid = threadIdx.x;
  const int lane = tid & 63;
  const int wv = tid >> 6;
  const int g = blockIdx.y;
  const int oh = blockIdx.z;
  const int v = blockIdx.x * 256 + tid;
  const int vbase = (v >> 10) * 9604 + ((v >> 5) & 31) * 98 + (v & 31);

  { // stage tap params (1024 float4s)
    const float4* src = (const float4*)(tpar + g * 4096);
    float4* dst = (float4*)tplds;
    #pragma unroll
    for (int j = 0; j < 4; ++j) dst[tid + j * 256] = src[tid + j * 256];
  }

  ZERO4(a0) ZERO4(a1) ZERO4(a2) ZERO4(a3) ZERO4(a4) ZERO4(a5) ZERO4(a6) ZERO4(a7)

  for (int half = 0; half < 2; ++half) {
    __syncthreads();
    { // stage weights for this K-half: 4096 floats
      const float4* src = (const float4*)(w1t + ((g * 2 + oh) * 256 + half * 128) * 32);
      float4* dst = (float4*)wlds;
      #pragma unroll
      for (int j = 0; j < 4; ++j) dst[tid + j * 256] = src[tid + j * 256];
    }
    __syncthreads();
    #pragma unroll 2
    for (int kk = 0; kk < 128; ++kk) {
      const int kt = half * 128 + kk;
      float4 t0 = *(const float4*)&tplds[kt * 16];
      float4 t1 = *(const float4*)&tplds[kt * 16 + 4];
      float4 t2 = *(const float4*)&tplds[kt * 16 + 8];
      float4 t3 = *(const float4*)&tplds[kt * 16 + 12];
      float xval;
      {
        const float* p  = pvol + (vbase + __float_as_int(t0.x));
        const float* pz = p + 9604;
        float h0 = p[0]  * t0.y + p[1]  * t0.z;
        float h1 = p[98] * t0.y + p[99] * t0.z;
        float h2 = pz[0]  * t0.y + pz[1]  * t0.z;
        float h3 = pz[98] * t0.y + pz[99] * t0.z;
        xval = h0 * t0.w + h1 * t1.x + h2 * t1.y + h3 * t1.z;
      }
      {
        const float* p  = pvol + (vbase + __float_as_int(t2.x));
        const float* pz = p + 9604;
        float h0 = p[0]  * t2.y + p[1]  * t2.z;
        float h1 = p[98] * t2.y + p[99] * t2.z;
        float h2 = pz[0]  * t2.y + pz[1]  * t2.z;
        float h3 = pz[98] * t2.y + pz[99] * t2.z;
        xval += h0 * t2.w + h1 * t3.x + h2 * t3.y + h3 * t3.z; // tap b pre-negated
      }
      const float4* wk = (const float4*)&wlds[kk * 32];
      float4 w;
      w = wk[0]; FMA4(a0, w, xval)
      w = wk[1]; FMA4(a1, w, xval)
      w = wk[2]; FMA4(a2, w, xval)
      w = wk[3]; FMA4(a3, w, xval)
      w = wk[4]; FMA4(a4, w, xval)
      w = wk[5]; FMA4(a5, w, xval)
      w = wk[6]; FMA4(a6, w, xval)
      w = wk[7]; FMA4(a7, w, xval)
    }
  }
  const int obase = (g << 6) + oh * 32;
  #define S1_ST(A, o0) \
    y[((size_t)(obase + (o0) + 0)) * VOXN + v] = (A).x; \
    y[((size_t)(obase + (o0) + 1)) * VOXN + v] = (A).y; \
    y[((size_t)(obase + (o0) + 2)) * VOXN + v] = (A).z; \
    y[((size_t)(obase + (o0) + 3)) * VOXN + v] = (A).w;
  S1_ST(a0, 0)  S1_ST(a1, 4)  S1_ST(a2, 8)  S1_ST(a3, 12)
  S1_ST(a4, 16) S1_ST(a5, 20) S1_ST(a6, 24) S1_ST(a7, 28)
  #undef S1_ST
  float ms = 0.f, mq = 0.f;
  STASH4(a0, 0)  STASH4(a1, 4)  STASH4(a2, 8)  STASH4(a3, 12)
  STASH4(a4, 16) STASH4(a5, 20) STASH4(a6, 24) STASH4(a7, 28)
  if (lane < 32) { redS[wv][lane] = ms; redQ[wv][lane] = mq; }
  __syncthreads();
  if (tid < 32) {
    float s = redS[0][tid] + redS[1][tid] + redS[2][tid] + redS[3][tid];
    float q = redQ[0][tid] + redQ[1][tid] + redQ[2][tid] + redQ[3][tid];
    atomicAdd(&stats_y[obase + tid], s);
    atomicAdd(&stats_y[256 + obase + tid], q);
  }
}

// ---------------- S2: x1 = relu(BN(y)); x2pre = w2 @ x1 (32 outputs/block) ----------------
__global__ __launch_bounds__(256) void s2_bn_gemm(
    const float* __restrict__ y, const float* __restrict__ stats_y,
    const float* __restrict__ g1, const float* __restrict__ b1,
    const float* __restrict__ w2t, float* __restrict__ x2p, float* __restrict__ stats_x2p)
{
  __shared__ float As[256], Bs[256];
  __shared__ float redS[4][32], redQ[4][32];
  const int tid = threadIdx.x;
  const int lane = tid & 63;
  const int wv = tid >> 6;
  {
    float m = stats_y[tid] * (1.f / VOXN);
    float vv = stats_y[256 + tid] * (1.f / VOXN) - m * m;
    float a = g1[tid] * rsqrtf(vv + 1e-5f);
    As[tid] = a; Bs[tid] = b1[tid] - m * a;
  }
  __syncthreads();
  const int q = blockIdx.y;            // 0..3 -> outputs q*32..+31
  const int n = blockIdx.x * 256 + tid;
  ZERO4(a0) ZERO4(a1) ZERO4(a2) ZERO4(a3) ZERO4(a4) ZERO4(a5) ZERO4(a6) ZERO4(a7)
  #pragma unroll 4
  for (int c = 0; c < 256; ++c) {
    float t = fmaxf(fmaf(y[(size_t)c * VOXN + n], As[c], Bs[c]), 0.f);
    const float4* wk = (const float4*)(w2t + c * 128 + q * 32);
    float4 w;
    w = wk[0]; FMA4(a0, w, t)
    w = wk[1]; FMA4(a1, w, t)
    w = wk[2]; FMA4(a2, w, t)
    w = wk[3]; FMA4(a3, w, t)
    w = wk[4]; FMA4(a4, w, t)
    w = wk[5]; FMA4(a5, w, t)
    w = wk[6]; FMA4(a6, w, t)
    w = wk[7]; FMA4(a7, w, t)
  }
  const int ob = q * 32;
  #define S2_ST(A, o0) \
    x2p[((size_t)(ob + (o0) + 0)) * VOXN + n] = (A).x; \
    x2p[((size_t)(ob + (o0) + 1)) * VOXN + n] = (A).y; \
    x2p[((size_t)(ob + (o0) + 2)) * VOXN + n] = (A).z; \
    x2p[((size_t)(ob + (o0) + 3)) * VOXN + n] = (A).w;
  S2_ST(a0, 0) S2_ST(a1, 4) S2_ST(a2, 8) S2_ST(a3, 12)
  S2_ST(a4, 16) S2_ST(a5, 20) S2_ST(a6, 24) S2_ST(a7, 28)
  #undef S2_ST
  float ms = 0.f, mq = 0.f;
  STASH4(a0, 0) STASH4(a1, 4) STASH4(a2, 8) STASH4(a3, 12)
  STASH4(a4, 16) STASH4(a5, 20) STASH4(a6, 24) STASH4(a7, 28)
  if (lane < 32) { redS[wv][lane] = ms; redQ[wv][lane] = mq; }
  __syncthreads();
  if (tid < 32) {
    float s = redS[0][tid] + redS[1][tid] + redS[2][tid] + redS[3][tid];
    float qq = redQ[0][tid] + redQ[1][tid] + redQ[2][tid] + redQ[3][tid];
    atomicAdd(&stats_x2p[ob + tid], s);
    atomicAdd(&stats_x2p[128 + ob + tid], qq);
  }
}

// ---------------- S3: x2 = BN(x2pre) -> H[0:128]; ha = relu(w3a@x2) -> H[128+qh*8 ..] ----------------
__global__ __launch_bounds__(256) void s3_x2_ha(
    const float* __restrict__ x2p, const float* __restrict__ stats_x2p,
    const float* __restrict__ g2, const float* __restrict__ b2,
    const float* __restrict__ w3at, float* __restrict__ H, float* __restrict__ stats_H)
{
  __shared__ float As[128], Bs[128];
  __shared__ float redS[4][8], redQ[4][8];
  const int tid = threadIdx.x;
  const int lane = tid & 63;
  const int wv = tid >> 6;
  if (tid < 128) {
    float m = stats_x2p[tid] * (1.f / VOXN);
    float vv = stats_x2p[128 + tid] * (1.f / VOXN) - m * m;
    float a = g2[tid] * rsqrtf(vv + 1e-5f);
    As[tid] = a; Bs[tid] = b2[tid] - m * a;
    if (blockIdx.x == 0 && blockIdx.y == 0) {
      float mean = b2[tid];
      float var = a * a * vv;
      stats_H[tid] = mean * (float)VOXN;
      stats_H[256 + tid] = (var + mean * mean) * (float)VOXN;
    }
  }
  __syncthreads();
  const int qh = blockIdx.y;           // 0..3 -> outputs 128+qh*8..+7
  const int n = blockIdx.x * 256 + tid;
  ZERO4(a0) ZERO4(a1)
  #pragma unroll 4
  for (int c = 0; c < 128; ++c) {
    float x2v = fmaf(x2p[(size_t)c * VOXN + n], As[c], Bs[c]);
    if (qh == 0) H[(size_t)c * VOXN + n] = x2v;
    const float4* wk = (const float4*)(w3at + c * 32 + qh * 8);
    float4 w;
    w = wk[0]; FMA4(a0, w, x2v)
    w = wk[1]; FMA4(a1, w, x2v)
  }
  RELU4(a0) RELU4(a1)
  const int ob = 128 + qh * 8;
  #define S3_ST(A, o0) \
    H[((size_t)(ob + (o0) + 0)) * VOXN + n] = (A).x; \
    H[((size_t)(ob + (o0) + 1)) * VOXN + n] = (A).y; \
    H[((size_t)(ob + (o0) + 2)) * VOXN + n] = (A).z; \
    H[((size_t)(ob + (o0) + 3)) * VOXN + n] = (A).w;
  S3_ST(a0, 0) S3_ST(a1, 4)
  #undef S3_ST
  float ms = 0.f, mq = 0.f;
  STASH4(a0, 0) STASH4(a1, 4)
  if (lane < 8) { redS[wv][lane] = ms; redQ[wv][lane] = mq; }
  __syncthreads();
  if (tid < 8) {
    float s = redS[0][tid] + redS[1][tid] + redS[2][tid] + redS[3][tid];
    float qq = redQ[0][tid] + redQ[1][tid] + redQ[2][tid] + redQ[3][tid];
    atomicAdd(&stats_H[ob + tid], s);
    atomicAdd(&stats_H[256 + ob + tid], qq);
  }
}

// ---------------- S4/5/6: h = relu(w @ BN(H[0:CIN])) -> H[och + qh*8 ..] ----------------
template<int CIN>
__global__ __launch_bounds__(256) void s_dense(
    const float* __restrict__ Hin, const float* __restrict__ stats_H,
    const float* __restrict__ g, const float* __restrict__ b,
    const float* __restrict__ wt, float* __restrict__ H, float* __restrict__ stats_out, int och)
{
  __shared__ float As[CIN], Bs[CIN];
  __shared__ float redS[4][8], redQ[4][8];
  const int tid = threadIdx.x;
  const int lane = tid & 63;
  const int wv = tid >> 6;
  if (tid < CIN) {
    float m = stats_H[tid] * (1.f / VOXN);
    float vv = stats_H[256 + tid] * (1.f / VOXN) - m * m;
    float a = g[tid] * rsqrtf(vv + 1e-5f);
    As[tid] = a; Bs[tid] = b[tid] - m * a;
  }
  __syncthreads();
  const int osub = blockIdx.y * 8;     // 0..3 -> 8 outputs
  const int n = blockIdx.x * 256 + tid;
  ZERO4(a0) ZERO4(a1)
  #pragma unroll 4
  for (int c = 0; c < CIN; ++c) {
    float t = fmaf(Hin[(size_t)c * VOXN + n], As[c], Bs[c]);
    const float4* wk = (const float4*)(wt + c * 32 + osub);
    float4 w;
    w = wk[0]; FMA4(a0, w, t)
    w = wk[1]; FMA4(a1, w, t)
  }
  RELU4(a0) RELU4(a1)
  const int ob = och + osub;
  #define SD_ST(A, o0) \
    H[((size_t)(ob + (o0) + 0)) * VOXN + n] = (A).x; \
    H[((size_t)(ob + (o0) + 1)) * VOXN + n] = (A).y; \
    H[((size_t)(ob + (o0) + 2)) * VOXN + n] = (A).z; \
    H[((size_t)(ob + (o0) + 3)) * VOXN + n] = (A).w;
  SD_ST(a0, 0) SD_ST(a1, 4)
  #undef SD_ST
  float ms = 0.f, mq = 0.f;
  STASH4(a0, 0) STASH4(a1, 4)
  if (lane < 8) { redS[wv][lane] = ms; redQ[wv][lane] = mq; }
  __syncthreads();
  if (tid < 8) {
    float s = redS[0][tid] + redS[1][tid] + redS[2][tid] + redS[3][tid];
    float qq = redQ[0][tid] + redQ[1][tid] + redQ[2][tid] + redQ[3][tid];
    atomicAdd(&stats_out[ob + tid], s);
    atomicAdd(&stats_out[256 + ob + tid], qq);
  }
}

// ---------------- S7: out = sigmoid(w4 @ BN(H) + b4) ----------------
__global__ __launch_bounds__(256) void s7_final(
    const float* __restrict__ H, const float* __restrict__ stats_H,
    const float* __restrict__ g3d, const float* __restrict__ b3d,
    const float* __restrict__ w4t, const float* __restrict__ b4, float* __restrict__ out)
{
  __shared__ float As[256], Bs[256];
  const int tid = threadIdx.x;
  {
    float m = stats_H[tid] * (1.f / VOXN);
    float vv = stats_H[256 + tid] * (1.f / VOXN) - m * m;
    float a = g3d[tid] * rsqrtf(vv + 1e-5f);
    As[tid] = a; Bs[tid] = b3d[tid] - m * a;
  }
  __syncthreads();
  const int n = blockIdx.x * 256 + tid;
  ZERO4(a0) ZERO4(a1)
  #pragma unroll 4
  for (int c = 0; c < 256; ++c) {
    float t = fmaf(H[(size_t)c * VOXN + n], As[c], Bs[c]);
    const float4* wk = (const float4*)(w4t + c * 8);
    float4 w;
    w = wk[0]; FMA4(a0, w, t)
    w = wk[1]; FMA4(a1, w, t)
  }
  out[(size_t)0 * VOXN + n] = 1.f / (1.f + expf(-(a0.x + b4[0])));
  out[(size_t)1 * VOXN + n] = 1.f / (1.f + expf(-(a0.y + b4[1])));
  out[(size_t)2 * VOXN + n] = 1.f / (1.f + expf(-(a0.z + b4[2])));
  out[(size_t)3 * VOXN + n] = 1.f / (1.f + expf(-(a0.w + b4[3])));
  out[(size_t)4 * VOXN + n] = 1.f / (1.f + expf(-(a1.x + b4[4])));
  out[(size_t)5 * VOXN + n] = 1.f / (1.f + expf(-(a1.y + b4[5])));
  out[(size_t)6 * VOXN + n] = 1.f / (1.f + expf(-(a1.z + b4[6])));
  out[(size_t)7 * VOXN + n] = 1.f / (1.f + expf(-(a1.w + b4[7])));
}

extern "C" void kernel_launch(void* const* d_in, const int* in_sizes, int n_in,
                              void* d_out, int out_size, void* d_ws, size_t ws_size,
                              hipStream_t stream)
{
  const float* images  = (const float*)d_in[0];
  const float* offset1 = (const float*)d_in[1];
  const float* w1  = (const float*)d_in[2];
  const float* g1  = (const float*)d_in[3];
  const float* b1  = (const float*)d_in[4];
  const float* w2  = (const float*)d_in[5];
  const float* g2  = (const float*)d_in[6];
  const float* b2  = (const float*)d_in[7];
  const float* w3a = (const float*)d_in[8];
  const float* w3b = (const float*)d_in[9];
  const float* w3c = (const float*)d_in[10];
  const float* w3d = (const float*)d_in[11];
  const float* g3a = (const float*)d_in[12];
  const float* b3a = (const float*)d_in[13];
  const float* g3b = (const float*)d_in[14];
  const float* b3b = (const float*)d_in[15];
  const float* g3c = (const float*)d_in[16];
  const float* b3c = (const float*)d_in[17];
  const float* g3d = (const float*)d_in[18];
  const float* b3d = (const float*)d_in[19];
  const float* w4  = (const float*)d_in[20];
  const float* b4  = (const float*)d_in[21];

  float* ws  = (float*)d_ws;
  float* out = (float*)d_out;

  float* statsY = ws + OFF_STATS_Y;
  float* statsX = ws + OFF_STATS_X2P;
  float* statsH = ws + OFF_STATS_H;
  float* pvol   = ws + OFF_PVOL;
  float* w1t    = ws + OFF_W1T;
  float* w2t    = ws + OFF_W2T;
  float* YH     = ws + OFF_YH;   // y, later H
  float* x2p    = ws + OFF_X2P;

  s0_setup<<<dim3(128), dim3(256), 0, stream>>>(images, offset1, w1, w2, w3a, w3b, w3c, w3d, w4, ws);
  s1_gather_gemm<<<dim3(128, 4, 2), dim3(256), 0, stream>>>(pvol, ws + OFF_TPAR, w1t, YH, statsY);
  s2_bn_gemm<<<dim3(128, 4), dim3(256), 0, stream>>>(YH, statsY, g1, b1, w2t, x2p, statsX);
  s3_x2_ha<<<dim3(128, 4), dim3(256), 0, stream>>>(x2p, statsX, g2, b2, ws + OFF_W3AT, YH, statsH);
  s_dense<160><<<dim3(128, 4), dim3(256), 0, stream>>>(YH, statsH, g3a, b3a, ws + OFF_W3BT, YH, statsH, 160);
  s_dense<192><<<dim3(128, 4), dim3(256), 0, stream>>>(YH, statsH, g3b, b3b, ws + OFF_W3CT, YH, statsH, 192);
  s_dense<224><<<dim3(128, 4), dim3(256), 0, stream>>>(YH, statsH, g3c, b3c, ws + OFF_W3DT, YH, statsH, 224);
  s7_final<<<dim3(128), dim3(256), 0, stream>>>(YH, statsH, g3d, b3d, ws + OFF_W4T, b4, out);
}

// Round 7
// 529.949 us; speedup vs baseline: 1.3379x; 1.3379x over previous
//
#include <hip/hip_runtime.h>
#include <math.h>

#define VOXN 32768

// ---- workspace layout (float offsets) ----
constexpr int OFF_STATS_Y   = 0;        // 512
constexpr int OFF_STATS_X2P = 512;      // 256
constexpr int OFF_STATS_H   = 768;      // 512
constexpr int OFF_TPAR      = 1280;     // 1024*16 packed tap params (SORTED order)
constexpr int OFF_W1T       = 17664;    // 65536: [g][cSorted(256)][o(64)]
constexpr int OFF_W2T       = 83200;    // 32768
constexpr int OFF_W3AT      = 115968;   // 4096
constexpr int OFF_W3BT      = 120064;   // 5120
constexpr int OFF_W3CT      = 125184;   // 6144
constexpr int OFF_W3DT      = 131328;   // 7168
constexpr int OFF_W4T       = 138496;   // 2048
constexpr int OFF_YH        = 140544;   // 8388608 (y, later H)
constexpr int OFF_C0A       = OFF_YH;       // 1024 ints (dead before s1 writes y)
constexpr int OFF_PERM      = OFF_YH + 1024;// 1024 ints
constexpr int OFF_X2P       = 8529152;  // 4194304 (x2pre; ALSO hosts pvolP early)
constexpr int OFF_PVOLP     = OFF_X2P;  // 941192 float2 = 1882384 floats, dead before s2

#define FMA4(A, W, X) { (A).x = fmaf((W).x, (X), (A).x); (A).y = fmaf((W).y, (X), (A).y); \
                        (A).z = fmaf((W).z, (X), (A).z); (A).w = fmaf((W).w, (X), (A).w); }
#define RELU4(A) { (A).x = fmaxf((A).x, 0.f); (A).y = fmaxf((A).y, 0.f); \
                   (A).z = fmaxf((A).z, 0.f); (A).w = fmaxf((A).w, 0.f); }
#define ZERO4(A) float4 A; (A).x = 0.f; (A).y = 0.f; (A).z = 0.f; (A).w = 0.f;

#define BFLY(s, q) { s += __shfl_xor(s, 32, 64); q += __shfl_xor(q, 32, 64); \
                     s += __shfl_xor(s, 16, 64); q += __shfl_xor(q, 16, 64); \
                     s += __shfl_xor(s,  8, 64); q += __shfl_xor(q,  8, 64); \
                     s += __shfl_xor(s,  4, 64); q += __shfl_xor(q,  4, 64); \
                     s += __shfl_xor(s,  2, 64); q += __shfl_xor(q,  2, 64); \
                     s += __shfl_xor(s,  1, 64); q += __shfl_xor(q,  1, 64); }
#define STASH1(V, O) { float s_ = (V), q_ = (V) * (V); BFLY(s_, q_) \
                       if (lane == (O)) { ms = s_; mq = q_; } }
#define STASH4(A, O0) STASH1((A).x, (O0)+0) STASH1((A).y, (O0)+1) \
                      STASH1((A).z, (O0)+2) STASH1((A).w, (O0)+3)

// decode padded-98^3 linear index -> volume value (0 outside interior)
__device__ __forceinline__ float pv_at(const float* __restrict__ images, int j) {
  int x = j % 98, t = j / 98, y = t % 98, z = t / 98;
  if (x >= 33 && x < 65 && y >= 33 && y < 65 && z >= 33 && z < 65)
    return images[((z - 33) * 32 + (y - 33)) * 32 + (x - 33)];
  return 0.f;
}

// compute c0 (linear base index in 98^3) for tap s of offset k
__device__ __forceinline__ int tap_c0(const float* __restrict__ offset1, int k, int s) {
  float ox = fminf(fmaxf(offset1[k * 6 + s * 3 + 0] * 16.f, -1000.f), 1000.f);
  float oy = fminf(fmaxf(offset1[k * 6 + s * 3 + 1] * 16.f, -1000.f), 1000.f);
  float oz = fminf(fmaxf(offset1[k * 6 + s * 3 + 2] * 16.f, -1000.f), 1000.f);
  int sx = (int)floorf(ox), sy = (int)floorf(oy), sz = (int)floorf(oz);
  bool valid = (sx >= -33 && sx <= 32) && (sy >= -33 && sy <= 32) && (sz >= -33 && sz <= 32);
  if (!valid) { sx = sy = sz = 0; }
  return (sz + 33) * 9604 + (sy + 33) * 98 + (sx + 33);
}

// ---------------- S0a: pvolP + c0 keys + small weight transposes + zero stats ----------------
__global__ void s0a_setup(const float* __restrict__ images, const float* __restrict__ offset1,
                          const float* __restrict__ w2,
                          const float* __restrict__ w3a, const float* __restrict__ w3b,
                          const float* __restrict__ w3c, const float* __restrict__ w3d,
                          const float* __restrict__ w4, float* __restrict__ ws)
{
  const int idx = blockIdx.x * blockDim.x + threadIdx.x;
  const int stride = gridDim.x * blockDim.x;
  for (int i = idx; i < 1280; i += stride) ws[i] = 0.f;
  float2* pp = (float2*)(ws + OFF_PVOLP);
  for (int i = idx; i < 941192; i += stride) {
    float v0 = pv_at(images, i);
    float v1 = (i + 1 < 941192) ? pv_at(images, i + 1) : 0.f;
    float2 f; f.x = v0; f.y = v1;
    pp[i] = f;
  }
  int* c0a = (int*)(ws + OFF_C0A);
  for (int k = idx; k < 1024; k += stride) c0a[k] = tap_c0(offset1, k, 0);
  for (int i = idx; i < 32768; i += stride) { int o = i & 127, c = i >> 7; ws[OFF_W2T + i] = w2[o * 256 + c]; }
  for (int i = idx; i < 4096;  i += stride) { int o = i & 31,  c = i >> 5; ws[OFF_W3AT + i] = w3a[o * 128 + c]; }
  for (int i = idx; i < 5120;  i += stride) { int o = i & 31,  c = i >> 5; ws[OFF_W3BT + i] = w3b[o * 160 + c]; }
  for (int i = idx; i < 6144;  i += stride) { int o = i & 31,  c = i >> 5; ws[OFF_W3CT + i] = w3c[o * 192 + c]; }
  for (int i = idx; i < 7168;  i += stride) { int o = i & 31,  c = i >> 5; ws[OFF_W3DT + i] = w3d[o * 224 + c]; }
  for (int i = idx; i < 2048;  i += stride) { int l = i & 7,   c = i >> 3; ws[OFF_W4T + i] = w4[l * 256 + c]; }
}

// ---------------- S0b: rank-sort taps by c0 within each group ----------------
__global__ void s0b_rank(float* __restrict__ ws)
{
  const int idx = blockIdx.x * blockDim.x + threadIdx.x; // 1024 threads: (g,k)
  if (idx >= 1024) return;
  const int g = idx >> 8, k = idx & 255;
  const int* c0a = (const int*)(ws + OFF_C0A);
  int* perm = (int*)(ws + OFF_PERM);
  const int my = c0a[g * 256 + k];
  int rank = 0;
  for (int j = 0; j < 256; ++j) {
    int cj = c0a[g * 256 + j];
    rank += (cj < my) || (cj == my && j < k);
  }
  perm[g * 256 + rank] = k;
}

// ---------------- S0c: permuted tap params + permuted w1 transpose ----------------
__global__ void s0c_build(const float* __restrict__ offset1, const float* __restrict__ w1,
                          float* __restrict__ ws)
{
  const int idx = blockIdx.x * blockDim.x + threadIdx.x;
  const int stride = gridDim.x * blockDim.x;
  const int* perm = (const int*)(ws + OFF_PERM);
  for (int p = idx; p < 1024; p += stride) {
    const int g = p >> 8;
    const int k = g * 256 + perm[p];
    float* tp = ws + OFF_TPAR + p * 16;
    for (int s = 0; s < 2; ++s) {
      float ox = fminf(fmaxf(offset1[k * 6 + s * 3 + 0] * 16.f, -1000.f), 1000.f);
      float oy = fminf(fmaxf(offset1[k * 6 + s * 3 + 1] * 16.f, -1000.f), 1000.f);
      float oz = fminf(fmaxf(offset1[k * 6 + s * 3 + 2] * 16.f, -1000.f), 1000.f);
      float fxf = floorf(ox), fyf = floorf(oy), fzf = floorf(oz);
      float fx = ox - fxf, fy = oy - fyf, fz = oz - fzf;
      int sx = (int)fxf, sy = (int)fyf, sz = (int)fzf;
      bool valid = (sx >= -33 && sx <= 32) && (sy >= -33 && sy <= 32) && (sz >= -33 && sz <= 32);
      if (!valid) { sx = sy = sz = 0; }
      float vm = valid ? 1.f : 0.f;
      int c0 = (sz + 33) * 9604 + (sy + 33) * 98 + (sx + 33);
      float sgn = s ? -1.f : 1.f;
      float wy0 = 1.f - fy, wy1 = fy, wz0 = 1.f - fz, wz1 = fz;
      tp[s * 8 + 0] = __int_as_float(c0);
      tp[s * 8 + 1] = vm * (1.f - fx);
      tp[s * 8 + 2] = vm * fx;
      tp[s * 8 + 3] = vm * sgn * wz0 * wy0;
      tp[s * 8 + 4] = vm * sgn * wz0 * wy1;
      tp[s * 8 + 5] = vm * sgn * wz1 * wy0;
      tp[s * 8 + 6] = vm * sgn * wz1 * wy1;
      tp[s * 8 + 7] = 0.f;
    }
  }
  // w1t: [g][cSorted][o64], column = perm[cSorted]
  for (int i = idx; i < 65536; i += stride) {
    int o = i & 63, t = i >> 6, c = t & 255, g = t >> 8;
    int ksrc = perm[g * 256 + c];
    ws[OFF_W1T + i] = w1[g * 16384 + o * 256 + ksrc];
  }
}

// ---------------- S1: fused gather + grouped GEMM ----------------
// 256 thr = 256 voxels, one group per blockIdx.y; 64 outputs (16 float4 accs).
// Gather via paired-float2 volume: 8 VMEM loads/k. Taps via uniform (scalar) loads.
__global__ __launch_bounds__(256) void s1_gather_gemm(
    const float2* __restrict__ pvolP, const float* __restrict__ tparP,
    const float* __restrict__ w1t, float* __restrict__ y, float* __restrict__ stats_y)
{
  __shared__ float wlds[128 * 64];    // 32 KB: half-K weight tile
  __shared__ float redS[4][64], redQ[4][64];
  const int tid = threadIdx.x;
  const int lane = tid & 63;
  const int wv = tid >> 6;
  const int g = blockIdx.y;
  const int v = blockIdx.x * 256 + tid;
  const int vbase = (v >> 10) * 9604 + ((v >> 5) & 31) * 98 + (v & 31);

  ZERO4(a0) ZERO4(a1) ZERO4(a2) ZERO4(a3) ZERO4(a4) ZERO4(a5) ZERO4(a6) ZERO4(a7)
  ZERO4(a8) ZERO4(a9) ZERO4(a10) ZERO4(a11) ZERO4(a12) ZERO4(a13) ZERO4(a14) ZERO4(a15)

  const float4* tq_base = (const float4*)(tparP + g * 4096); // uniform per block

  for (int half = 0; half < 2; ++half) {
    __syncthreads();
    { // stage weights for this K-half: 8192 floats
      const float4* src = (const float4*)(w1t + ((size_t)g * 256 + half * 128) * 64);
      float4* dst = (float4*)wlds;
      #pragma unroll
      for (int j = 0; j < 8; ++j) dst[tid + j * 256] = src[tid + j * 256];
    }
    __syncthreads();
    #pragma unroll 2
    for (int kk = 0; kk < 128; ++kk) {
      const int kt = half * 128 + kk;
      float4 t0 = tq_base[kt * 4 + 0];   // uniform address -> scalar loads
      float4 t1 = tq_base[kt * 4 + 1];
      float4 t2 = tq_base[kt * 4 + 2];
      float4 t3 = tq_base[kt * 4 + 3];
      float xval;
      {
        const float2* p = pvolP + (vbase + __float_as_int(t0.x));
        float2 r0 = p[0], r1 = p[98], r2 = p[9604], r3 = p[9702];
        float h0 = r0.x * t0.y + r0.y * t0.z;
        float h1 = r1.x * t0.y + r1.y * t0.z;
        float h2 = r2.x * t0.y + r2.y * t0.z;
        float h3 = r3.x * t0.y + r3.y * t0.z;
        xval = h0 * t0.w + h1 * t1.x + h2 * t1.y + h3 * t1.z;
      }
      {
        const float2* p = pvolP + (vbase + __float_as_int(t2.x));
        float2 r0 = p[0], r1 = p[98], r2 = p[9604], r3 = p[9702];
        float h0 = r0.x * t2.y + r0.y * t2.z;
        float h1 = r1.x * t2.y + r1.y * t2.z;
        float h2 = r2.x * t2.y + r2.y * t2.z;
        float h3 = r3.x * t2.y + r3.y * t2.z;
        xval += h0 * t2.w + h1 * t3.x + h2 * t3.y + h3 * t3.z; // tap b pre-negated
      }
      const float4* wk = (const float4*)&wlds[kk * 64];
      float4 w;
      w = wk[0];  FMA4(a0,  w, xval)
      w = wk[1];  FMA4(a1,  w, xval)
      w = wk[2];  FMA4(a2,  w, xval)
      w = wk[3];  FMA4(a3,  w, xval)
      w = wk[4];  FMA4(a4,  w, xval)
      w = wk[5];  FMA4(a5,  w, xval)
      w = wk[6];  FMA4(a6,  w, xval)
      w = wk[7];  FMA4(a7,  w, xval)
      w = wk[8];  FMA4(a8,  w, xval)
      w = wk[9];  FMA4(a9,  w, xval)
      w = wk[10]; FMA4(a10, w, xval)
      w = wk[11]; FMA4(a11, w, xval)
      w = wk[12]; FMA4(a12, w, xval)
      w = wk[13]; FMA4(a13, w, xval)
      w = wk[14]; FMA4(a14, w, xval)
      w = wk[15]; FMA4(a15, w, xval)
    }
  }
  const int obase = g << 6;
  #define S1_ST(A, o0) \
    y[((size_t)(obase + (o0) + 0)) * VOXN + v] = (A).x; \
    y[((size_t)(obase + (o0) + 1)) * VOXN + v] = (A).y; \
    y[((size_t)(obase + (o0) + 2)) * VOXN + v] = (A).z; \
    y[((size_t)(obase + (o0) + 3)) * VOXN + v] = (A).w;
  S1_ST(a0, 0)   S1_ST(a1, 4)   S1_ST(a2, 8)   S1_ST(a3, 12)
  S1_ST(a4, 16)  S1_ST(a5, 20)  S1_ST(a6, 24)  S1_ST(a7, 28)
  S1_ST(a8, 32)  S1_ST(a9, 36)  S1_ST(a10, 40) S1_ST(a11, 44)
  S1_ST(a12, 48) S1_ST(a13, 52) S1_ST(a14, 56) S1_ST(a15, 60)
  #undef S1_ST
  float ms = 0.f, mq = 0.f;
  STASH4(a0, 0)   STASH4(a1, 4)   STASH4(a2, 8)   STASH4(a3, 12)
  STASH4(a4, 16)  STASH4(a5, 20)  STASH4(a6, 24)  STASH4(a7, 28)
  STASH4(a8, 32)  STASH4(a9, 36)  STASH4(a10, 40) STASH4(a11, 44)
  STASH4(a12, 48) STASH4(a13, 52) STASH4(a14, 56) STASH4(a15, 60)
  redS[wv][lane] = ms; redQ[wv][lane] = mq;
  __syncthreads();
  if (tid < 64) {
    float s = redS[0][tid] + redS[1][tid] + redS[2][tid] + redS[3][tid];
    float q = redQ[0][tid] + redQ[1][tid] + redQ[2][tid] + redQ[3][tid];
    atomicAdd(&stats_y[obase + tid], s);
    atomicAdd(&stats_y[256 + obase + tid], q);
  }
}

// ---------------- S2: x1 = relu(BN(y)); x2pre = w2 @ x1 (32 outputs/block) ----------------
__global__ __launch_bounds__(256) void s2_bn_gemm(
    const float* __restrict__ y, const float* __restrict__ stats_y,
    const float* __restrict__ g1, const float* __restrict__ b1,
    const float* __restrict__ w2t, float* __restrict__ x2p, float* __restrict__ stats_x2p)
{
  __shared__ float As[256], Bs[256];
  __shared__ float redS[4][32], redQ[4][32];
  const int tid = threadIdx.x;
  const int lane = tid & 63;
  const int wv = tid >> 6;
  {
    float m = stats_y[tid] * (1.f / VOXN);
    float vv = stats_y[256 + tid] * (1.f / VOXN) - m * m;
    float a = g1[tid] * rsqrtf(vv + 1e-5f);
    As[tid] = a; Bs[tid] = b1[tid] - m * a;
  }
  __syncthreads();
  const int q = blockIdx.y;            // 0..3 -> outputs q*32..+31
  const int n = blockIdx.x * 256 + tid;
  ZERO4(a0) ZERO4(a1) ZERO4(a2) ZERO4(a3) ZERO4(a4) ZERO4(a5) ZERO4(a6) ZERO4(a7)
  #pragma unroll 4
  for (int c = 0; c < 256; ++c) {
    float t = fmaxf(fmaf(y[(size_t)c * VOXN + n], As[c], Bs[c]), 0.f);
    const float4* wk = (const float4*)(w2t + c * 128 + q * 32);
    float4 w;
    w = wk[0]; FMA4(a0, w, t)
    w = wk[1]; FMA4(a1, w, t)
    w = wk[2]; FMA4(a2, w, t)
    w = wk[3]; FMA4(a3, w, t)
    w = wk[4]; FMA4(a4, w, t)
    w = wk[5]; FMA4(a5, w, t)
    w = wk[6]; FMA4(a6, w, t)
    w = wk[7]; FMA4(a7, w, t)
  }
  const int ob = q * 32;
  #define S2_ST(A, o0) \
    x2p[((size_t)(ob + (o0) + 0)) * VOXN + n] = (A).x; \
    x2p[((size_t)(ob + (o0) + 1)) * VOXN + n] = (A).y; \
    x2p[((size_t)(ob + (o0) + 2)) * VOXN + n] = (A).z; \
    x2p[((size_t)(ob + (o0) + 3)) * VOXN + n] = (A).w;
  S2_ST(a0, 0) S2_ST(a1, 4) S2_ST(a2, 8) S2_ST(a3, 12)
  S2_ST(a4, 16) S2_ST(a5, 20) S2_ST(a6, 24) S2_ST(a7, 28)
  #undef S2_ST
  float ms = 0.f, mq = 0.f;
  STASH4(a0, 0) STASH4(a1, 4) STASH4(a2, 8) STASH4(a3, 12)
  STASH4(a4, 16) STASH4(a5, 20) STASH4(a6, 24) STASH4(a7, 28)
  if (lane < 32) { redS[wv][lane] = ms; redQ[wv][lane] = mq; }
  __syncthreads();
  if (tid < 32) {
    float s = redS[0][tid] + redS[1][tid] + redS[2][tid] + redS[3][tid];
    float qq = redQ[0][tid] + redQ[1][tid] + redQ[2][tid] + redQ[3][tid];
    atomicAdd(&stats_x2p[ob + tid], s);
    atomicAdd(&stats_x2p[128 + ob + tid], qq);
  }
}

// ---------------- S3: x2 = BN(x2pre) -> H[0:128]; ha = relu(w3a@x2) -> H[128+qh*8 ..] ----------------
__global__ __launch_bounds__(256) void s3_x2_ha(
    const float* __restrict__ x2p, const float* __restrict__ stats_x2p,
    const float* __restrict__ g2, const float* __restrict__ b2,
    const float* __restrict__ w3at, float* __restrict__ H, float* __restrict__ stats_H)
{
  __shared__ float As[128], Bs[128];
  __shared__ float redS[4][8], redQ[4][8];
  const int tid = threadIdx.x;
  const int lane = tid & 63;
  const int wv = tid >> 6;
  if (tid < 128) {
    float m = stats_x2p[tid] * (1.f / VOXN);
    float vv = stats_x2p[128 + tid] * (1.f / VOXN) - m * m;
    float a = g2[tid] * rsqrtf(vv + 1e-5f);
    As[tid] = a; Bs[tid] = b2[tid] - m * a;
    if (blockIdx.x == 0 && blockIdx.y == 0) {
      float mean = b2[tid];
      float var = a * a * vv;
      stats_H[tid] = mean * (float)VOXN;
      stats_H[256 + tid] = (var + mean * mean) * (float)VOXN;
    }
  }
  __syncthreads();
  const int qh = blockIdx.y;           // 0..3 -> outputs 128+qh*8..+7
  const int n = blockIdx.x * 256 + tid;
  ZERO4(a0) ZERO4(a1)
  #pragma unroll 4
  for (int c = 0; c < 128; ++c) {
    float x2v = fmaf(x2p[(size_t)c * VOXN + n], As[c], Bs[c]);
    if (qh == 0) H[(size_t)c * VOXN + n] = x2v;
    const float4* wk = (const float4*)(w3at + c * 32 + qh * 8);
    float4 w;
    w = wk[0]; FMA4(a0, w, x2v)
    w = wk[1]; FMA4(a1, w, x2v)
  }
  RELU4(a0) RELU4(a1)
  const int ob = 128 + qh * 8;
  #define S3_ST(A, o0) \
    H[((size_t)(ob + (o0) + 0)) * VOXN + n] = (A).x; \
    H[((size_t)(ob + (o0) + 1)) * VOXN + n] = (A).y; \
    H[((size_t)(ob + (o0) + 2)) * VOXN + n] = (A).z; \
    H[((size_t)(ob + (o0) + 3)) * VOXN + n] = (A).w;
  S3_ST(a0, 0) S3_ST(a1, 4)
  #undef S3_ST
  float ms = 0.f, mq = 0.f;
  STASH4(a0, 0) STASH4(a1, 4)
  if (lane < 8) { redS[wv][lane] = ms; redQ[wv][lane] = mq; }
  __syncthreads();
  if (tid < 8) {
    float s = redS[0][tid] + redS[1][tid] + redS[2][tid] + redS[3][tid];
    float qq = redQ[0][tid] + redQ[1][tid] + redQ[2][tid] + redQ[3][tid];
    atomicAdd(&stats_H[ob + tid], s);
    atomicAdd(&stats_H[256 + ob + tid], qq);
  }
}

// ---------------- S4/5/6: h = relu(w @ BN(H[0:CIN])) -> H[och + qh*8 ..] ----------------
template<int CIN>
__global__ __launch_bounds__(256) void s_dense(
    const float* __restrict__ Hin, const float* __restrict__ stats_H,
    const float* __restrict__ g, const float* __restrict__ b,
    const float* __restrict__ wt, float* __restrict__ H, float* __restrict__ stats_out, int och)
{
  __shared__ float As[CIN], Bs[CIN];
  __shared__ float redS[4][8], redQ[4][8];
  const int tid = threadIdx.x;
  const int lane = tid & 63;
  const int wv = tid >> 6;
  if (tid < CIN) {
    float m = stats_H[tid] * (1.f / VOXN);
    float vv = stats_H[256 + tid] * (1.f / VOXN) - m * m;
    float a = g[tid] * rsqrtf(vv + 1e-5f);
    As[tid] = a; Bs[tid] = b[tid] - m * a;
  }
  __syncthreads();
  const int osub = blockIdx.y * 8;     // 0..3 -> 8 outputs
  const int n = blockIdx.x * 256 + tid;
  ZERO4(a0) ZERO4(a1)
  #pragma unroll 4
  for (int c = 0; c < CIN; ++c) {
    float t = fmaf(Hin[(size_t)c * VOXN + n], As[c], Bs[c]);
    const float4* wk = (const float4*)(wt + c * 32 + osub);
    float4 w;
    w = wk[0]; FMA4(a0, w, t)
    w = wk[1]; FMA4(a1, w, t)
  }
  RELU4(a0) RELU4(a1)
  const int ob = och + osub;
  #define SD_ST(A, o0) \
    H[((size_t)(ob + (o0) + 0)) * VOXN + n] = (A).x; \
    H[((size_t)(ob + (o0) + 1)) * VOXN + n] = (A).y; \
    H[((size_t)(ob + (o0) + 2)) * VOXN + n] = (A).z; \
    H[((size_t)(ob + (o0) + 3)) * VOXN + n] = (A).w;
  SD_ST(a0, 0) SD_ST(a1, 4)
  #undef SD_ST
  float ms = 0.f, mq = 0.f;
  STASH4(a0, 0) STASH4(a1, 4)
  if (lane < 8) { redS[wv][lane] = ms; redQ[wv][lane] = mq; }
  __syncthreads();
  if (tid < 8) {
    float s = redS[0][tid] + redS[1][tid] + redS[2][tid] + redS[3][tid];
    float qq = redQ[0][tid] + redQ[1][tid] + redQ[2][tid] + redQ[3][tid];
    atomicAdd(&stats_out[ob + tid], s);
    atomicAdd(&stats_out[256 + ob + tid], qq);
  }
}

// ---------------- S7: out = sigmoid(w4 @ BN(H) + b4) ----------------
__global__ __launch_bounds__(256) void s7_final(
    const float* __restrict__ H, const float* __restrict__ stats_H,
    const float* __restrict__ g3d, const float* __restrict__ b3d,
    const float* __restrict__ w4t, const float* __restrict__ b4, float* __restrict__ out)
{
  __shared__ float As[256], Bs[256];
  const int tid = threadIdx.x;
  {
    float m = stats_H[tid] * (1.f / VOXN);
    float vv = stats_H[256 + tid] * (1.f / VOXN) - m * m;
    float a = g3d[tid] * rsqrtf(vv + 1e-5f);
    As[tid] = a; Bs[tid] = b3d[tid] - m * a;
  }
  __syncthreads();
  const int n = blockIdx.x * 256 + tid;
  ZERO4(a0) ZERO4(a1)
  #pragma unroll 4
  for (int c = 0; c < 256; ++c) {
    float t = fmaf(H[(size_t)c * VOXN + n], As[c], Bs[c]);
    const float4* wk = (const float4*)(w4t + c * 8);
    float4 w;
    w = wk[0]; FMA4(a0, w, t)
    w = wk[1]; FMA4(a1, w, t)
  }
  out[(size_t)0 * VOXN + n] = 1.f / (1.f + expf(-(a0.x + b4[0])));
  out[(size_t)1 * VOXN + n] = 1.f / (1.f + expf(-(a0.y + b4[1])));
  out[(size_t)2 * VOXN + n] = 1.f / (1.f + expf(-(a0.z + b4[2])));
  out[(size_t)3 * VOXN + n] = 1.f / (1.f + expf(-(a0.w + b4[3])));
  out[(size_t)4 * VOXN + n] = 1.f / (1.f + expf(-(a1.x + b4[4])));
  out[(size_t)5 * VOXN + n] = 1.f / (1.f + expf(-(a1.y + b4[5])));
  out[(size_t)6 * VOXN + n] = 1.f / (1.f + expf(-(a1.z + b4[6])));
  out[(size_t)7 * VOXN + n] = 1.f / (1.f + expf(-(a1.w + b4[7])));
}

extern "C" void kernel_launch(void* const* d_in, const int* in_sizes, int n_in,
                              void* d_out, int out_size, void* d_ws, size_t ws_size,
                              hipStream_t stream)
{
  const float* images  = (const float*)d_in[0];
  const float* offset1 = (const float*)d_in[1];
  const float* w1  = (const float*)d_in[2];
  const float* g1  = (const float*)d_in[3];
  const float* b1  = (const float*)d_in[4];
  const float* w2  = (const float*)d_in[5];
  const float* g2  = (const float*)d_in[6];
  const float* b2  = (const float*)d_in[7];
  const float* w3a = (const float*)d_in[8];
  const float* w3b = (const float*)d_in[9];
  const float* w3c = (const float*)d_in[10];
  const float* w3d = (const float*)d_in[11];
  const float* g3a = (const float*)d_in[12];
  const float* b3a = (const float*)d_in[13];
  const float* g3b = (const float*)d_in[14];
  const float* b3b = (const float*)d_in[15];
  const float* g3c = (const float*)d_in[16];
  const float* b3c = (const float*)d_in[17];
  const float* g3d = (const float*)d_in[18];
  const float* b3d = (const float*)d_in[19];
  const float* w4  = (const float*)d_in[20];
  const float* b4  = (const float*)d_in[21];

  float* ws  = (float*)d_ws;
  float* out = (float*)d_out;

  float* statsY = ws + OFF_STATS_Y;
  float* statsX = ws + OFF_STATS_X2P;
  float* statsH = ws + OFF_STATS_H;
  float* w1t    = ws + OFF_W1T;
  float* w2t    = ws + OFF_W2T;
  float* YH     = ws + OFF_YH;   // y, later H
  float* x2p    = ws + OFF_X2P;

  s0a_setup<<<dim3(128), dim3(256), 0, stream>>>(images, offset1, w2, w3a, w3b, w3c, w3d, w4, ws);
  s0b_rank<<<dim3(4), dim3(256), 0, stream>>>(ws);
  s0c_build<<<dim3(64), dim3(256), 0, stream>>>(offset1, w1, ws);
  s1_gather_gemm<<<dim3(128, 4), dim3(256), 0, stream>>>(
      (const float2*)(ws + OFF_PVOLP), ws + OFF_TPAR, w1t, YH, statsY);
  s2_bn_gemm<<<dim3(128, 4), dim3(256), 0, stream>>>(YH, statsY, g1, b1, w2t, x2p, statsX);
  s3_x2_ha<<<dim3(128, 4), dim3(256), 0, stream>>>(x2p, statsX, g2, b2, ws + OFF_W3AT, YH, statsH);
  s_dense<160><<<dim3(128, 4), dim3(256), 0, stream>>>(YH, statsH, g3a, b3a, ws + OFF_W3BT, YH, statsH, 160);
  s_dense<192><<<dim3(128, 4), dim3(256), 0, stream>>>(YH, statsH, g3b, b3b, ws + OFF_W3CT, YH, statsH, 192);
  s_dense<224><<<dim3(128, 4), dim3(256), 0, stream>>>(YH, statsH, g3c, b3c, ws + OFF_W3DT, YH, statsH, 224);
  s7_final<<<dim3(128), dim3(256), 0, stream>>>(YH, statsH, g3d, b3d, ws + OFF_W4T, b4, out);
}

// Round 8
// 469.954 us; speedup vs baseline: 1.5087x; 1.1277x over previous
//
#include <hip/hip_runtime.h>
#include <math.h>

#define VOXN 32768

// ---- workspace layout (float offsets) ----
constexpr int OFF_STATS_Y   = 0;        // 512
constexpr int OFF_STATS_X2P = 512;      // 256
constexpr int OFF_STATS_H   = 768;      // 512
constexpr int OFF_TPAR      = 1280;     // 1024*16 packed tap params (SORTED order)
constexpr int OFF_W1T       = 17664;    // 65536: [g][cSorted(256)][o(64)]
constexpr int OFF_W2T       = 83200;    // 32768
constexpr int OFF_W3AT      = 115968;   // 4096
constexpr int OFF_W3BT      = 120064;   // 5120
constexpr int OFF_W3CT      = 125184;   // 6144
constexpr int OFF_W3DT      = 131328;   // 7168
constexpr int OFF_W4T       = 138496;   // 2048
constexpr int OFF_YH        = 140544;   // 8388608 (y, later H)
constexpr int OFF_C0A       = OFF_YH;       // 1024 ints (dead before s1 writes y)
constexpr int OFF_PERM      = OFF_YH + 1024;// 1024 ints
constexpr int OFF_X2P       = 8529152;  // 4194304 (x2pre; ALSO hosts pvolP early)
constexpr int OFF_PVOLP     = OFF_X2P;  // 941192 float2, dead before s2

#define FMA4(A, W, X) { (A).x = fmaf((W).x, (X), (A).x); (A).y = fmaf((W).y, (X), (A).y); \
                        (A).z = fmaf((W).z, (X), (A).z); (A).w = fmaf((W).w, (X), (A).w); }
#define ADD4(A, T) { (A).x += (T).x; (A).y += (T).y; (A).z += (T).z; (A).w += (T).w; }
#define RELU4(A) { (A).x = fmaxf((A).x, 0.f); (A).y = fmaxf((A).y, 0.f); \
                   (A).z = fmaxf((A).z, 0.f); (A).w = fmaxf((A).w, 0.f); }
#define ZERO4(A) float4 A; (A).x = 0.f; (A).y = 0.f; (A).z = 0.f; (A).w = 0.f;

#define BFLY(s, q) { s += __shfl_xor(s, 32, 64); q += __shfl_xor(q, 32, 64); \
                     s += __shfl_xor(s, 16, 64); q += __shfl_xor(q, 16, 64); \
                     s += __shfl_xor(s,  8, 64); q += __shfl_xor(q,  8, 64); \
                     s += __shfl_xor(s,  4, 64); q += __shfl_xor(q,  4, 64); \
                     s += __shfl_xor(s,  2, 64); q += __shfl_xor(q,  2, 64); \
                     s += __shfl_xor(s,  1, 64); q += __shfl_xor(q,  1, 64); }
#define STASH1(V, O) { float s_ = (V), q_ = (V) * (V); BFLY(s_, q_) \
                       if (lane == (O)) { ms = s_; mq = q_; } }
#define STASH4(A, O0) STASH1((A).x, (O0)+0) STASH1((A).y, (O0)+1) \
                      STASH1((A).z, (O0)+2) STASH1((A).w, (O0)+3)

__device__ __forceinline__ float pv_at(const float* __restrict__ images, int j) {
  int x = j % 98, t = j / 98, y = t % 98, z = t / 98;
  if (x >= 33 && x < 65 && y >= 33 && y < 65 && z >= 33 && z < 65)
    return images[((z - 33) * 32 + (y - 33)) * 32 + (x - 33)];
  return 0.f;
}

__device__ __forceinline__ int tap_c0(const float* __restrict__ offset1, int k, int s) {
  float ox = fminf(fmaxf(offset1[k * 6 + s * 3 + 0] * 16.f, -1000.f), 1000.f);
  float oy = fminf(fmaxf(offset1[k * 6 + s * 3 + 1] * 16.f, -1000.f), 1000.f);
  float oz = fminf(fmaxf(offset1[k * 6 + s * 3 + 2] * 16.f, -1000.f), 1000.f);
  int sx = (int)floorf(ox), sy = (int)floorf(oy), sz = (int)floorf(oz);
  bool valid = (sx >= -33 && sx <= 32) && (sy >= -33 && sy <= 32) && (sz >= -33 && sz <= 32);
  if (!valid) { sx = sy = sz = 0; }
  return (sz + 33) * 9604 + (sy + 33) * 98 + (sx + 33);
}

// ---------------- S0a ----------------
__global__ void s0a_setup(const float* __restrict__ images, const float* __restrict__ offset1,
                          const float* __restrict__ w2,
                          const float* __restrict__ w3a, const float* __restrict__ w3b,
                          const float* __restrict__ w3c, const float* __restrict__ w3d,
                          const float* __restrict__ w4, float* __restrict__ ws)
{
  const int idx = blockIdx.x * blockDim.x + threadIdx.x;
  const int stride = gridDim.x * blockDim.x;
  for (int i = idx; i < 1280; i += stride) ws[i] = 0.f;
  float2* pp = (float2*)(ws + OFF_PVOLP);
  for (int i = idx; i < 941192; i += stride) {
    float v0 = pv_at(images, i);
    float v1 = (i + 1 < 941192) ? pv_at(images, i + 1) : 0.f;
    float2 f; f.x = v0; f.y = v1;
    pp[i] = f;
  }
  int* c0a = (int*)(ws + OFF_C0A);
  for (int k = idx; k < 1024; k += stride) c0a[k] = tap_c0(offset1, k, 0);
  for (int i = idx; i < 32768; i += stride) { int o = i & 127, c = i >> 7; ws[OFF_W2T + i] = w2[o * 256 + c]; }
  for (int i = idx; i < 4096;  i += stride) { int o = i & 31,  c = i >> 5; ws[OFF_W3AT + i] = w3a[o * 128 + c]; }
  for (int i = idx; i < 5120;  i += stride) { int o = i & 31,  c = i >> 5; ws[OFF_W3BT + i] = w3b[o * 160 + c]; }
  for (int i = idx; i < 6144;  i += stride) { int o = i & 31,  c = i >> 5; ws[OFF_W3CT + i] = w3c[o * 192 + c]; }
  for (int i = idx; i < 7168;  i += stride) { int o = i & 31,  c = i >> 5; ws[OFF_W3DT + i] = w3d[o * 224 + c]; }
  for (int i = idx; i < 2048;  i += stride) { int l = i & 7,   c = i >> 3; ws[OFF_W4T + i] = w4[l * 256 + c]; }
}

// ---------------- S0b: rank-sort taps by c0 within each group ----------------
__global__ void s0b_rank(float* __restrict__ ws)
{
  const int idx = blockIdx.x * blockDim.x + threadIdx.x;
  if (idx >= 1024) return;
  const int g = idx >> 8, k = idx & 255;
  const int* c0a = (const int*)(ws + OFF_C0A);
  int* perm = (int*)(ws + OFF_PERM);
  const int my = c0a[g * 256 + k];
  int rank = 0;
  for (int j = 0; j < 256; ++j) {
    int cj = c0a[g * 256 + j];
    rank += (cj < my) || (cj == my && j < k);
  }
  perm[g * 256 + rank] = k;
}

// ---------------- S0c: permuted tap params + permuted w1 transpose ----------------
__global__ void s0c_build(const float* __restrict__ offset1, const float* __restrict__ w1,
                          float* __restrict__ ws)
{
  const int idx = blockIdx.x * blockDim.x + threadIdx.x;
  const int stride = gridDim.x * blockDim.x;
  const int* perm = (const int*)(ws + OFF_PERM);
  for (int p = idx; p < 1024; p += stride) {
    const int g = p >> 8;
    const int k = g * 256 + perm[p];
    float* tp = ws + OFF_TPAR + p * 16;
    for (int s = 0; s < 2; ++s) {
      float ox = fminf(fmaxf(offset1[k * 6 + s * 3 + 0] * 16.f, -1000.f), 1000.f);
      float oy = fminf(fmaxf(offset1[k * 6 + s * 3 + 1] * 16.f, -1000.f), 1000.f);
      float oz = fminf(fmaxf(offset1[k * 6 + s * 3 + 2] * 16.f, -1000.f), 1000.f);
      float fxf = floorf(ox), fyf = floorf(oy), fzf = floorf(oz);
      float fx = ox - fxf, fy = oy - fyf, fz = oz - fzf;
      int sx = (int)fxf, sy = (int)fyf, sz = (int)fzf;
      bool valid = (sx >= -33 && sx <= 32) && (sy >= -33 && sy <= 32) && (sz >= -33 && sz <= 32);
      if (!valid) { sx = sy = sz = 0; }
      float vm = valid ? 1.f : 0.f;
      int c0 = (sz + 33) * 9604 + (sy + 33) * 98 + (sx + 33);
      float sgn = s ? -1.f : 1.f;
      float wy0 = 1.f - fy, wy1 = fy, wz0 = 1.f - fz, wz1 = fz;
      tp[s * 8 + 0] = __int_as_float(c0);
      tp[s * 8 + 1] = vm * (1.f - fx);
      tp[s * 8 + 2] = vm * fx;
      tp[s * 8 + 3] = vm * sgn * wz0 * wy0;
      tp[s * 8 + 4] = vm * sgn * wz0 * wy1;
      tp[s * 8 + 5] = vm * sgn * wz1 * wy0;
      tp[s * 8 + 6] = vm * sgn * wz1 * wy1;
      tp[s * 8 + 7] = 0.f;
    }
  }
  for (int i = idx; i < 65536; i += stride) {
    int o = i & 63, t = i >> 6, c = t & 255, g = t >> 8;
    int ksrc = perm[g * 256 + c];
    ws[OFF_W1T + i] = w1[g * 16384 + o * 256 + ksrc];
  }
}

// ---------------- S1: fused gather + grouped GEMM, dual-k-half 8-wave blocks ----------------
// Block 512 thr: waves 0-3 k[0:128), waves 4-7 k[128:256), same 256 voxels.
// Each (k,v) gathered exactly once; 16 waves/CU. LDS: 2x8KB weight chunks,
// reused as the sub1->sub0 combine buffer.
__global__ __launch_bounds__(512, 4) void s1_gather_gemm(
    const float2* __restrict__ pvolP, const float* __restrict__ tparP,
    const float* __restrict__ w1t, float* __restrict__ y, float* __restrict__ stats_y)
{
  __shared__ float wlds[2][32 * 64];      // 16 KB
  __shared__ float redS[4][64], redQ[4][64];
  const int tid = threadIdx.x;
  const int lane = tid & 63;
  const int wv = tid >> 6;       // 0..7
  const int sub = wv >> 2;       // k-half
  const int vw = wv & 3;         // voxel-wave within subgroup
  const int g = blockIdx.y;
  const int v = blockIdx.x * 256 + vw * 64 + lane;
  const int vbase = (v >> 10) * 9604 + ((v >> 5) & 31) * 98 + (v & 31);
  const int sidx = vw * 64 + lane;          // 0..255 within subgroup
  const int kb0 = sub * 128;

  ZERO4(a0) ZERO4(a1) ZERO4(a2) ZERO4(a3) ZERO4(a4) ZERO4(a5) ZERO4(a6) ZERO4(a7)
  ZERO4(a8) ZERO4(a9) ZERO4(a10) ZERO4(a11) ZERO4(a12) ZERO4(a13) ZERO4(a14) ZERO4(a15)

  const float4* tq_base = (const float4*)(tparP + g * 4096);

  for (int ch = 0; ch < 4; ++ch) {
    __syncthreads();
    { // stage this subgroup's 32-k weight chunk (512 float4s per subgroup)
      const float4* src = (const float4*)(w1t + ((size_t)(g * 256 + kb0 + ch * 32)) * 64);
      float4* dst = (float4*)&wlds[sub][0];
      dst[sidx] = src[sidx];
      dst[sidx + 256] = src[sidx + 256];
    }
    __syncthreads();
    #pragma unroll 2
    for (int kk = 0; kk < 32; ++kk) {
      const int kt = kb0 + ch * 32 + kk;
      float4 t0 = tq_base[kt * 4 + 0];
      float4 t1 = tq_base[kt * 4 + 1];
      float4 t2 = tq_base[kt * 4 + 2];
      float4 t3 = tq_base[kt * 4 + 3];
      float xval;
      {
        const float2* p = pvolP + (vbase + __float_as_int(t0.x));
        float2 r0 = p[0], r1 = p[98], r2 = p[9604], r3 = p[9702];
        float h0 = r0.x * t0.y + r0.y * t0.z;
        float h1 = r1.x * t0.y + r1.y * t0.z;
        float h2 = r2.x * t0.y + r2.y * t0.z;
        float h3 = r3.x * t0.y + r3.y * t0.z;
        xval = h0 * t0.w + h1 * t1.x + h2 * t1.y + h3 * t1.z;
      }
      {
        const float2* p = pvolP + (vbase + __float_as_int(t2.x));
        float2 r0 = p[0], r1 = p[98], r2 = p[9604], r3 = p[9702];
        float h0 = r0.x * t2.y + r0.y * t2.z;
        float h1 = r1.x * t2.y + r1.y * t2.z;
        float h2 = r2.x * t2.y + r2.y * t2.z;
        float h3 = r3.x * t2.y + r3.y * t2.z;
        xval += h0 * t2.w + h1 * t3.x + h2 * t3.y + h3 * t3.z; // tap b pre-negated
      }
      const float4* wk = (const float4*)&wlds[sub][kk * 64];
      float4 w;
      w = wk[0];  FMA4(a0,  w, xval)
      w = wk[1];  FMA4(a1,  w, xval)
      w = wk[2];  FMA4(a2,  w, xval)
      w = wk[3];  FMA4(a3,  w, xval)
      w = wk[4];  FMA4(a4,  w, xval)
      w = wk[5];  FMA4(a5,  w, xval)
      w = wk[6];  FMA4(a6,  w, xval)
      w = wk[7];  FMA4(a7,  w, xval)
      w = wk[8];  FMA4(a8,  w, xval)
      w = wk[9];  FMA4(a9,  w, xval)
      w = wk[10]; FMA4(a10, w, xval)
      w = wk[11]; FMA4(a11, w, xval)
      w = wk[12]; FMA4(a12, w, xval)
      w = wk[13]; FMA4(a13, w, xval)
      w = wk[14]; FMA4(a14, w, xval)
      w = wk[15]; FMA4(a15, w, xval)
    }
  }
  // ---- combine sub1 partials into sub0 via LDS (4 rounds x 4 float4) ----
  __syncthreads();                         // compute fully done before reuse
  float4* cbuf = (float4*)&wlds[0][0];     // 1024 float4 = 16 KB
  #define CROUND(A0, A1, A2, A3) \
    if (sub == 1) { int bi = sidx * 4; \
      cbuf[bi] = A0; cbuf[bi + 1] = A1; cbuf[bi + 2] = A2; cbuf[bi + 3] = A3; } \
    __syncthreads(); \
    if (sub == 0) { int bi = sidx * 4; float4 t_; \
      t_ = cbuf[bi];     ADD4(A0, t_) \
      t_ = cbuf[bi + 1]; ADD4(A1, t_) \
      t_ = cbuf[bi + 2]; ADD4(A2, t_) \
      t_ = cbuf[bi + 3]; ADD4(A3, t_) } \
    __syncthreads();
  CROUND(a0, a1, a2, a3)
  CROUND(a4, a5, a6, a7)
  CROUND(a8, a9, a10, a11)
  CROUND(a12, a13, a14, a15)
  #undef CROUND

  const int obase = g << 6;
  if (sub == 0) {
    #define S1_ST(A, o0) \
      y[((size_t)(obase + (o0) + 0)) * VOXN + v] = (A).x; \
      y[((size_t)(obase + (o0) + 1)) * VOXN + v] = (A).y; \
      y[((size_t)(obase + (o0) + 2)) * VOXN + v] = (A).z; \
      y[((size_t)(obase + (o0) + 3)) * VOXN + v] = (A).w;
    S1_ST(a0, 0)   S1_ST(a1, 4)   S1_ST(a2, 8)   S1_ST(a3, 12)
    S1_ST(a4, 16)  S1_ST(a5, 20)  S1_ST(a6, 24)  S1_ST(a7, 28)
    S1_ST(a8, 32)  S1_ST(a9, 36)  S1_ST(a10, 40) S1_ST(a11, 44)
    S1_ST(a12, 48) S1_ST(a13, 52) S1_ST(a14, 56) S1_ST(a15, 60)
    #undef S1_ST
    float ms = 0.f, mq = 0.f;
    STASH4(a0, 0)   STASH4(a1, 4)   STASH4(a2, 8)   STASH4(a3, 12)
    STASH4(a4, 16)  STASH4(a5, 20)  STASH4(a6, 24)  STASH4(a7, 28)
    STASH4(a8, 32)  STASH4(a9, 36)  STASH4(a10, 40) STASH4(a11, 44)
    STASH4(a12, 48) STASH4(a13, 52) STASH4(a14, 56) STASH4(a15, 60)
    redS[vw][lane] = ms; redQ[vw][lane] = mq;
  }
  __syncthreads();
  if (tid < 64) {
    float s = redS[0][tid] + redS[1][tid] + redS[2][tid] + redS[3][tid];
    float q = redQ[0][tid] + redQ[1][tid] + redQ[2][tid] + redQ[3][tid];
    atomicAdd(&stats_y[obase + tid], s);
    atomicAdd(&stats_y[256 + obase + tid], q);
  }
}

// ---------------- S2: x1 = relu(BN(y)); x2pre = w2 @ x1 (32 outputs/block) ----------------
__global__ __launch_bounds__(256) void s2_bn_gemm(
    const float* __restrict__ y, const float* __restrict__ stats_y,
    const float* __restrict__ g1, const float* __restrict__ b1,
    const float* __restrict__ w2t, float* __restrict__ x2p, float* __restrict__ stats_x2p)
{
  __shared__ float As[256], Bs[256];
  __shared__ float redS[4][32], redQ[4][32];
  const int tid = threadIdx.x;
  const int lane = tid & 63;
  const int wv = tid >> 6;
  {
    float m = stats_y[tid] * (1.f / VOXN);
    float vv = stats_y[256 + tid] * (1.f / VOXN) - m * m;
    float a = g1[tid] * rsqrtf(vv + 1e-5f);
    As[tid] = a; Bs[tid] = b1[tid] - m * a;
  }
  __syncthreads();
  const int q = blockIdx.y;
  const int n = blockIdx.x * 256 + tid;
  ZERO4(a0) ZERO4(a1) ZERO4(a2) ZERO4(a3) ZERO4(a4) ZERO4(a5) ZERO4(a6) ZERO4(a7)
  #pragma unroll 4
  for (int c = 0; c < 256; ++c) {
    float t = fmaxf(fmaf(y[(size_t)c * VOXN + n], As[c], Bs[c]), 0.f);
    const float4* wk = (const float4*)(w2t + c * 128 + q * 32);
    float4 w;
    w = wk[0]; FMA4(a0, w, t)
    w = wk[1]; FMA4(a1, w, t)
    w = wk[2]; FMA4(a2, w, t)
    w = wk[3]; FMA4(a3, w, t)
    w = wk[4]; FMA4(a4, w, t)
    w = wk[5]; FMA4(a5, w, t)
    w = wk[6]; FMA4(a6, w, t)
    w = wk[7]; FMA4(a7, w, t)
  }
  const int ob = q * 32;
  #define S2_ST(A, o0) \
    x2p[((size_t)(ob + (o0) + 0)) * VOXN + n] = (A).x; \
    x2p[((size_t)(ob + (o0) + 1)) * VOXN + n] = (A).y; \
    x2p[((size_t)(ob + (o0) + 2)) * VOXN + n] = (A).z; \
    x2p[((size_t)(ob + (o0) + 3)) * VOXN + n] = (A).w;
  S2_ST(a0, 0) S2_ST(a1, 4) S2_ST(a2, 8) S2_ST(a3, 12)
  S2_ST(a4, 16) S2_ST(a5, 20) S2_ST(a6, 24) S2_ST(a7, 28)
  #undef S2_ST
  float ms = 0.f, mq = 0.f;
  STASH4(a0, 0) STASH4(a1, 4) STASH4(a2, 8) STASH4(a3, 12)
  STASH4(a4, 16) STASH4(a5, 20) STASH4(a6, 24) STASH4(a7, 28)
  if (lane < 32) { redS[wv][lane] = ms; redQ[wv][lane] = mq; }
  __syncthreads();
  if (tid < 32) {
    float s = redS[0][tid] + redS[1][tid] + redS[2][tid] + redS[3][tid];
    float qq = redQ[0][tid] + redQ[1][tid] + redQ[2][tid] + redQ[3][tid];
    atomicAdd(&stats_x2p[ob + tid], s);
    atomicAdd(&stats_x2p[128 + ob + tid], qq);
  }
}

// ---------------- S3 ----------------
__global__ __launch_bounds__(256) void s3_x2_ha(
    const float* __restrict__ x2p, const float* __restrict__ stats_x2p,
    const float* __restrict__ g2, const float* __restrict__ b2,
    const float* __restrict__ w3at, float* __restrict__ H, float* __restrict__ stats_H)
{
  __shared__ float As[128], Bs[128];
  __shared__ float redS[4][8], redQ[4][8];
  const int tid = threadIdx.x;
  const int lane = tid & 63;
  const int wv = tid >> 6;
  if (tid < 128) {
    float m = stats_x2p[tid] * (1.f / VOXN);
    float vv = stats_x2p[128 + tid] * (1.f / VOXN) - m * m;
    float a = g2[tid] * rsqrtf(vv + 1e-5f);
    As[tid] = a; Bs[tid] = b2[tid] - m * a;
    if (blockIdx.x == 0 && blockIdx.y == 0) {
      float mean = b2[tid];
      float var = a * a * vv;
      stats_H[tid] = mean * (float)VOXN;
      stats_H[256 + tid] = (var + mean * mean) * (float)VOXN;
    }
  }
  __syncthreads();
  const int qh = blockIdx.y;
  const int n = blockIdx.x * 256 + tid;
  ZERO4(a0) ZERO4(a1)
  #pragma unroll 8
  for (int c = 0; c < 128; ++c) {
    float x2v = fmaf(x2p[(size_t)c * VOXN + n], As[c], Bs[c]);
    if (qh == 0) H[(size_t)c * VOXN + n] = x2v;
    const float4* wk = (const float4*)(w3at + c * 32 + qh * 8);
    float4 w;
    w = wk[0]; FMA4(a0, w, x2v)
    w = wk[1]; FMA4(a1, w, x2v)
  }
  RELU4(a0) RELU4(a1)
  const int ob = 128 + qh * 8;
  #define S3_ST(A, o0) \
    H[((size_t)(ob + (o0) + 0)) * VOXN + n] = (A).x; \
    H[((size_t)(ob + (o0) + 1)) * VOXN + n] = (A).y; \
    H[((size_t)(ob + (o0) + 2)) * VOXN + n] = (A).z; \
    H[((size_t)(ob + (o0) + 3)) * VOXN + n] = (A).w;
  S3_ST(a0, 0) S3_ST(a1, 4)
  #undef S3_ST
  float ms = 0.f, mq = 0.f;
  STASH4(a0, 0) STASH4(a1, 4)
  if (lane < 8) { redS[wv][lane] = ms; redQ[wv][lane] = mq; }
  __syncthreads();
  if (tid < 8) {
    float s = redS[0][tid] + redS[1][tid] + redS[2][tid] + redS[3][tid];
    float qq = redQ[0][tid] + redQ[1][tid] + redQ[2][tid] + redQ[3][tid];
    atomicAdd(&stats_H[ob + tid], s);
    atomicAdd(&stats_H[256 + ob + tid], qq);
  }
}

// ---------------- S4/5/6 ----------------
template<int CIN>
__global__ __launch_bounds__(256) void s_dense(
    const float* __restrict__ Hin, const float* __restrict__ stats_H,
    const float* __restrict__ g, const float* __restrict__ b,
    const float* __restrict__ wt, float* __restrict__ H, float* __restrict__ stats_out, int och)
{
  __shared__ float As[CIN], Bs[CIN];
  __shared__ float redS[4][8], redQ[4][8];
  const int tid = threadIdx.x;
  const int lane = tid & 63;
  const int wv = tid >> 6;
  if (tid < CIN) {
    float m = stats_H[tid] * (1.f / VOXN);
    float vv = stats_H[256 + tid] * (1.f / VOXN) - m * m;
    float a = g[tid] * rsqrtf(vv + 1e-5f);
    As[tid] = a; Bs[tid] = b[tid] - m * a;
  }
  __syncthreads();
  const int osub = blockIdx.y * 8;
  const int n = blockIdx.x * 256 + tid;
  ZERO4(a0) ZERO4(a1)
  #pragma unroll 8
  for (int c = 0; c < CIN; ++c) {
    float t = fmaf(Hin[(size_t)c * VOXN + n], As[c], Bs[c]);
    const float4* wk = (const float4*)(wt + c * 32 + osub);
    float4 w;
    w = wk[0]; FMA4(a0, w, t)
    w = wk[1]; FMA4(a1, w, t)
  }
  RELU4(a0) RELU4(a1)
  const int ob = och + osub;
  #define SD_ST(A, o0) \
    H[((size_t)(ob + (o0) + 0)) * VOXN + n] = (A).x; \
    H[((size_t)(ob + (o0) + 1)) * VOXN + n] = (A).y; \
    H[((size_t)(ob + (o0) + 2)) * VOXN + n] = (A).z; \
    H[((size_t)(ob + (o0) + 3)) * VOXN + n] = (A).w;
  SD_ST(a0, 0) SD_ST(a1, 4)
  #undef SD_ST
  float ms = 0.f, mq = 0.f;
  STASH4(a0, 0) STASH4(a1, 4)
  if (lane < 8) { redS[wv][lane] = ms; redQ[wv][lane] = mq; }
  __syncthreads();
  if (tid < 8) {
    float s = redS[0][tid] + redS[1][tid] + redS[2][tid] + redS[3][tid];
    float qq = redQ[0][tid] + redQ[1][tid] + redQ[2][tid] + redQ[3][tid];
    atomicAdd(&stats_out[ob + tid], s);
    atomicAdd(&stats_out[256 + ob + tid], qq);
  }
}

// ---------------- S7 ----------------
__global__ __launch_bounds__(256) void s7_final(
    const float* __restrict__ H, const float* __restrict__ stats_H,
    const float* __restrict__ g3d, const float* __restrict__ b3d,
    const float* __restrict__ w4t, const float* __restrict__ b4, float* __restrict__ out)
{
  __shared__ float As[256], Bs[256];
  const int tid = threadIdx.x;
  {
    float m = stats_H[tid] * (1.f / VOXN);
    float vv = stats_H[256 + tid] * (1.f / VOXN) - m * m;
    float a = g3d[tid] * rsqrtf(vv + 1e-5f);
    As[tid] = a; Bs[tid] = b3d[tid] - m * a;
  }
  __syncthreads();
  const int n = blockIdx.x * 256 + tid;
  ZERO4(a0) ZERO4(a1)
  #pragma unroll 8
  for (int c = 0; c < 256; ++c) {
    float t = fmaf(H[(size_t)c * VOXN + n], As[c], Bs[c]);
    const float4* wk = (const float4*)(w4t + c * 8);
    float4 w;
    w = wk[0]; FMA4(a0, w, t)
    w = wk[1]; FMA4(a1, w, t)
  }
  out[(size_t)0 * VOXN + n] = 1.f / (1.f + expf(-(a0.x + b4[0])));
  out[(size_t)1 * VOXN + n] = 1.f / (1.f + expf(-(a0.y + b4[1])));
  out[(size_t)2 * VOXN + n] = 1.f / (1.f + expf(-(a0.z + b4[2])));
  out[(size_t)3 * VOXN + n] = 1.f / (1.f + expf(-(a0.w + b4[3])));
  out[(size_t)4 * VOXN + n] = 1.f / (1.f + expf(-(a1.x + b4[4])));
  out[(size_t)5 * VOXN + n] = 1.f / (1.f + expf(-(a1.y + b4[5])));
  out[(size_t)6 * VOXN + n] = 1.f / (1.f + expf(-(a1.z + b4[6])));
  out[(size_t)7 * VOXN + n] = 1.f / (1.f + expf(-(a1.w + b4[7])));
}

extern "C" void kernel_launch(void* const* d_in, const int* in_sizes, int n_in,
                              void* d_out, int out_size, void* d_ws, size_t ws_size,
                              hipStream_t stream)
{
  const float* images  = (const float*)d_in[0];
  const float* offset1 = (const float*)d_in[1];
  const float* w1  = (const float*)d_in[2];
  const float* g1  = (const float*)d_in[3];
  const float* b1  = (const float*)d_in[4];
  const float* w2  = (const float*)d_in[5];
  const float* g2  = (const float*)d_in[6];
  const float* b2  = (const float*)d_in[7];
  const float* w3a = (const float*)d_in[8];
  const float* w3b = (const float*)d_in[9];
  const float* w3c = (const float*)d_in[10];
  const float* w3d = (const float*)d_in[11];
  const float* g3a = (const float*)d_in[12];
  const float* b3a = (const float*)d_in[13];
  const float* g3b = (const float*)d_in[14];
  const float* b3b = (const float*)d_in[15];
  const float* g3c = (const float*)d_in[16];
  const float* b3c = (const float*)d_in[17];
  const float* g3d = (const float*)d_in[18];
  const float* b3d = (const float*)d_in[19];
  const float* w4  = (const float*)d_in[20];
  const float* b4  = (const float*)d_in[21];

  float* ws  = (float*)d_ws;
  float* out = (float*)d_out;

  float* statsY = ws + OFF_STATS_Y;
  float* statsX = ws + OFF_STATS_X2P;
  float* statsH = ws + OFF_STATS_H;
  float* w1t    = ws + OFF_W1T;
  float* w2t    = ws + OFF_W2T;
  float* YH     = ws + OFF_YH;   // y, later H
  float* x2p    = ws + OFF_X2P;

  s0a_setup<<<dim3(128), dim3(256), 0, stream>>>(images, offset1, w2, w3a, w3b, w3c, w3d, w4, ws);
  s0b_rank<<<dim3(4), dim3(256), 0, stream>>>(ws);
  s0c_build<<<dim3(64), dim3(256), 0, stream>>>(offset1, w1, ws);
  s1_gather_gemm<<<dim3(128, 4), dim3(512), 0, stream>>>(
      (const float2*)(ws + OFF_PVOLP), ws + OFF_TPAR, w1t, YH, statsY);
  s2_bn_gemm<<<dim3(128, 4), dim3(256), 0, stream>>>(YH, statsY, g1, b1, w2t, x2p, statsX);
  s3_x2_ha<<<dim3(128, 4), dim3(256), 0, stream>>>(x2p, statsX, g2, b2, ws + OFF_W3AT, YH, statsH);
  s_dense<160><<<dim3(128, 4), dim3(256), 0, stream>>>(YH, statsH, g3a, b3a, ws + OFF_W3BT, YH, statsH, 160);
  s_dense<192><<<dim3(128, 4), dim3(256), 0, stream>>>(YH, statsH, g3b, b3b, ws + OFF_W3CT, YH, statsH, 192);
  s_dense<224><<<dim3(128, 4), dim3(256), 0, stream>>>(YH, statsH, g3c, b3c, ws + OFF_W3DT, YH, statsH, 224);
  s7_final<<<dim3(128), dim3(256), 0, stream>>>(YH, statsH, g3d, b3d, ws + OFF_W4T, b4, out);
}